// Round 1
// baseline (204.050 us; speedup 1.0000x reference)
//
#include <hip/hip_runtime.h>
#include <cstdint>
#include <cstddef>

#define DEVI __device__ __forceinline__

typedef __bf16 bf16_t;
typedef __bf16 bf16x4 __attribute__((ext_vector_type(4)));
typedef __bf16 bf16x8 __attribute__((ext_vector_type(8)));
typedef float  f32x4  __attribute__((ext_vector_type(4)));
typedef unsigned short u16x4 __attribute__((ext_vector_type(4)));

static constexpr int Bz = 2, S = 2048, E = 1024, H = 16, Dh = 64;
static constexpr int M  = Bz * S;   // 4096 tokens
static constexpr int N  = H * Dh;   // 1024
static constexpr int Kd = E;        // 1024

DEVI unsigned short f2bf(float f) {
  unsigned u = __builtin_bit_cast(unsigned, f);
  return (unsigned short)((u + 0x7fffu + ((u >> 16) & 1u)) >> 16);
}

DEVI void async_copy16(void* lds, const void* g) {
  __builtin_amdgcn_global_load_lds((__attribute__((address_space(1))) void*)(g),
                                   (__attribute__((address_space(3))) void*)(lds), 16, 0, 0);
}

#define VMCNT8() asm volatile("s_waitcnt vmcnt(8)" ::: "memory")
#define VMCNT0() asm volatile("s_waitcnt vmcnt(0)" ::: "memory")

// ---------------- fused prep: convx | wtrans | rope table ----------------
__global__ void prep_kernel(const float* __restrict__ x, bf16_t* __restrict__ xb,
                            const float* __restrict__ Wq, const float* __restrict__ Wk,
                            const float* __restrict__ Wv, const float* __restrict__ Wo,
                            bf16_t* __restrict__ WtBase,
                            float* __restrict__ ropeC, float* __restrict__ ropeS) {
  __shared__ unsigned short tile[64][68];
  const int blk = blockIdx.x, tid = threadIdx.x;
  if (blk < 4096) {
    // x fp32 -> bf16
    int i = blk * 256 + tid;
    float4 v = ((const float4*)x)[i];
    u16x4 o = { f2bf(v.x), f2bf(v.y), f2bf(v.z), f2bf(v.w) };
    ((u16x4*)xb)[i] = o;
  } else if (blk < 5120) {
    // weight fp32 [K][N] -> bf16 [N][K]
    const int i = blk - 4096;
    const int z = i >> 8, rest = i & 255;
    const int n0 = (rest & 15) * 64, k0 = (rest >> 4) * 64;
    const float* W = (z == 0) ? Wq : (z == 1) ? Wk : (z == 2) ? Wv : Wo;
    unsigned short* T = (unsigned short*)(WtBase + (size_t)z * Kd * N);
    for (int e = tid; e < 1024; e += 256) {
      int r = e >> 4, c4 = (e & 15) * 4;
      float4 v = *(const float4*)(W + (size_t)(k0 + r) * N + n0 + c4);
      u16x4 o = { f2bf(v.x), f2bf(v.y), f2bf(v.z), f2bf(v.w) };
      *(u16x4*)&tile[r][c4] = o;
    }
    __syncthreads();
    for (int e = tid; e < 1024; e += 256) {
      int r = e >> 4, c4 = (e & 15) * 4;
      u16x4 o = { tile[c4][r], tile[c4 + 1][r], tile[c4 + 2][r], tile[c4 + 3][r] };
      *(u16x4*)&T[(size_t)(n0 + r) * Kd + k0 + c4] = o;
    }
  } else {
    int i = (blk - 5120) * 256 + tid;            // 65536 = 2048*32
    int pos = i >> 5, j = i & 31;
    float inv = exp2f(-(float)j * 0.41524101186092029f);   // log2(10000)/32
    float ang = (float)pos * inv;
    ropeC[i] = cosf(ang);
    ropeS[i] = sinf(ang);
  }
}

// bf16 [BH][S][D] -> bf16 [BH][D][S]
__global__ void vtrans_kernel(const bf16_t* __restrict__ V, bf16_t* __restrict__ Vt) {
  __shared__ unsigned short tile[64][68];
  const int bh = blockIdx.y;
  const int s0 = blockIdx.x * 64;
  const unsigned short* Vp = (const unsigned short*)V + (size_t)bh * S * Dh;
  unsigned short* Tp = (unsigned short*)Vt + (size_t)bh * Dh * S;
  const int tid = threadIdx.x;
  for (int e = tid; e < 1024; e += 256) {
    int r = e >> 4, c4 = (e & 15) * 4;
    u16x4 v = *(const u16x4*)(Vp + (size_t)(s0 + r) * Dh + c4);
    *(u16x4*)&tile[r][c4] = v;
  }
  __syncthreads();
  for (int e = tid; e < 1024; e += 256) {
    int d = e >> 4, s4 = (e & 15) * 4;
    u16x4 o = { tile[s4][d], tile[s4 + 1][d], tile[s4 + 2][d], tile[s4 + 3][d] };
    *(u16x4*)&Tp[(size_t)d * S + s0 + s4] = o;
  }
}

// ---------------- GEMM core (128x128 tile, BK=32, global_load_lds) ----------------

DEVI void gemm_mainloop(const bf16_t* __restrict__ A, const bf16_t* __restrict__ Bt,
                        bf16_t* sA, bf16_t* sB, int m0, int n0, f32x4 (&acc)[4][4]) {
  const int tid  = threadIdx.x;
  const int lane = tid & 63;
  const int wid  = tid >> 6;
  const int l16  = lane & 15;
  const int quad = lane >> 4;
  const int wm = (wid >> 1) * 64;
  const int wn = (wid & 1) * 64;
  const int o0 = wid * 2048 + lane * 16;   // byte offset within 8KB tile
  const int o1 = o0 + 1024;
  const int r0 = o0 >> 6, c0 = o0 & 63;
  const int r1 = o1 >> 6, c1 = o1 & 63;
  const char* Ab = (const char*)A;
  const char* Bb = (const char*)Bt;
  char* sAc = (char*)sA;
  char* sBc = (char*)sB;

  for (int k0 = 0; k0 < Kd; k0 += 32) {
    __syncthreads();
    async_copy16(sAc + wid * 2048,        Ab + ((size_t)(m0 + r0) * Kd + k0) * 2 + c0);
    async_copy16(sAc + wid * 2048 + 1024, Ab + ((size_t)(m0 + r1) * Kd + k0) * 2 + c1);
    async_copy16(sBc + wid * 2048,        Bb + ((size_t)(n0 + r0) * Kd + k0) * 2 + c0);
    async_copy16(sBc + wid * 2048 + 1024, Bb + ((size_t)(n0 + r1) * Kd + k0) * 2 + c1);
    __syncthreads();
    bf16x8 af[4], bfv[4];
#pragma unroll
    for (int mi = 0; mi < 4; ++mi)
      af[mi] = *(const bf16x8*)(sA + (wm + mi * 16 + l16) * 32 + quad * 8);
#pragma unroll
    for (int ni = 0; ni < 4; ++ni)
      bfv[ni] = *(const bf16x8*)(sB + (wn + ni * 16 + l16) * 32 + quad * 8);
#pragma unroll
    for (int mi = 0; mi < 4; ++mi)
#pragma unroll
      for (int ni = 0; ni < 4; ++ni)
        acc[mi][ni] = __builtin_amdgcn_mfma_f32_16x16x32_bf16(af[mi], bfv[ni], acc[mi][ni], 0, 0, 0);
  }
}

// z = 0:Q(RoPE+scale) 1:K(RoPE) 2:V ; out layout [B,H,S,D] bf16
__global__ __launch_bounds__(256, 3) void gemm_qkv_kernel(
    const bf16_t* __restrict__ xb, const bf16_t* __restrict__ WtBase,
    const float* __restrict__ bq, const float* __restrict__ bk, const float* __restrict__ bv,
    bf16_t* __restrict__ outBase,
    const float* __restrict__ ropeC, const float* __restrict__ ropeS) {
  __shared__ bf16_t sA[4096], sB[4096];
  const int z = blockIdx.z;
  const bf16_t* Bt = WtBase + (size_t)z * Kd * N;
  const float* bias = (z == 0) ? bq : (z == 1) ? bk : bv;
  unsigned short* outp = (unsigned short*)(outBase + (size_t)z * M * N);
  const int n0 = blockIdx.x * 128, m0 = blockIdx.y * 128;
  f32x4 acc[4][4] = {};
  gemm_mainloop(xb, Bt, sA, sB, m0, n0, acc);

  const int tid = threadIdx.x, lane = tid & 63, wid = tid >> 6;
  const int l16 = lane & 15, quad = lane >> 4;
  const int wm = (wid >> 1) * 64, wn = (wid & 1) * 64;
  const int cbase = n0 + wn;          // 64-aligned -> one head per wave slab
  const int h = cbase >> 6;

  if (z < 2) {
    // Q gets 0.125 (=1/sqrt(D)) * log2(e) folded in so attention can use exp2
    const float qs = (z == 0) ? 0.18033688011112042f : 1.0f;
#pragma unroll
    for (int mi = 0; mi < 4; ++mi)
#pragma unroll
      for (int r = 0; r < 4; ++r) {
        int t = m0 + wm + mi * 16 + quad * 4 + r;
        int bb = t >> 11, s = t & (S - 1);
        size_t obase = ((size_t)(bb * H + h) * S + s) * Dh;
#pragma unroll
        for (int np = 0; np < 2; ++np) {
          int j = np * 16 + l16;                 // = d (low half), d-32 (high half)
          float cc = ropeC[s * 32 + j];
          float ss = ropeS[s * 32 + j];
          float xlo = acc[mi][np][r]     + bias[cbase + j];
          float xhi = acc[mi][np + 2][r] + bias[cbase + j + 32];
          outp[obase + j]      = f2bf((xlo * cc - xhi * ss) * qs);
          outp[obase + j + 32] = f2bf((xhi * cc + xlo * ss) * qs);
        }
      }
  } else {
#pragma unroll
    for (int mi = 0; mi < 4; ++mi)
#pragma unroll
      for (int r = 0; r < 4; ++r) {
        int t = m0 + wm + mi * 16 + quad * 4 + r;
        int bb = t >> 11, s = t & (S - 1);
        size_t obase = ((size_t)(bb * H + h) * S + s) * Dh;
#pragma unroll
        for (int ni = 0; ni < 4; ++ni) {
          int d = ni * 16 + l16;
          outp[obase + d] = f2bf(acc[mi][ni][r] + bias[cbase + d]);
        }
      }
  }
}

// output GEMM: 64(m) x 128(n) tiles -> 512 blocks (2/CU)
__global__ __launch_bounds__(256, 4) void gemm_o_kernel(
    const bf16_t* __restrict__ A, const bf16_t* __restrict__ Bt,
    const float* __restrict__ bias, float* __restrict__ out) {
  __shared__ bf16_t sA[2048], sB[4096];     // 4KB A (64x32), 8KB B (128x32)
  const int n0 = blockIdx.x * 128, m0 = blockIdx.y * 64;
  const int tid = threadIdx.x, lane = tid & 63, wid = tid >> 6;
  const int l16 = lane & 15, quad = lane >> 4;
  const int wm = (wid >> 1) * 32, wn = (wid & 1) * 64;
  const int rowoff = lane >> 2, col8 = (lane & 3) * 8;
  const char* Ab = (const char*)A;
  const char* Bb = (const char*)Bt;
  char* sAc = (char*)sA;
  char* sBc = (char*)sB;
  f32x4 acc[2][4] = {};

  for (int k0 = 0; k0 < Kd; k0 += 32) {
    __syncthreads();
    async_copy16(sAc + wid * 1024,
                 Ab + ((size_t)(m0 + wid * 16 + rowoff) * Kd + k0 + col8) * 2);
    async_copy16(sBc + (wid * 2) * 1024,
                 Bb + ((size_t)(n0 + wid * 32 + rowoff) * Kd + k0 + col8) * 2);
    async_copy16(sBc + (wid * 2 + 1) * 1024,
                 Bb + ((size_t)(n0 + wid * 32 + 16 + rowoff) * Kd + k0 + col8) * 2);
    __syncthreads();
    bf16x8 af[2], bfv[4];
#pragma unroll
    for (int mi = 0; mi < 2; ++mi)
      af[mi] = *(const bf16x8*)(sA + (wm + mi * 16 + l16) * 32 + quad * 8);
#pragma unroll
    for (int ni = 0; ni < 4; ++ni)
      bfv[ni] = *(const bf16x8*)(sB + (wn + ni * 16 + l16) * 32 + quad * 8);
#pragma unroll
    for (int mi = 0; mi < 2; ++mi)
#pragma unroll
      for (int ni = 0; ni < 4; ++ni)
        acc[mi][ni] = __builtin_amdgcn_mfma_f32_16x16x32_bf16(af[mi], bfv[ni], acc[mi][ni], 0, 0, 0);
  }
#pragma unroll
  for (int mi = 0; mi < 2; ++mi)
#pragma unroll
    for (int r = 0; r < 4; ++r) {
      int t = m0 + wm + mi * 16 + quad * 4 + r;
#pragma unroll
      for (int ni = 0; ni < 4; ++ni) {
        int c = n0 + wn + ni * 16 + l16;
        out[(size_t)t * N + c] = acc[mi][ni][r] + bias[c];
      }
    }
}

// ---------------- flash attention ----------------
// 512 blocks: block (j, bh) handles q-tiles qbS=j and qbL=31-j of head bh.
// nS + nL == 17 for every pair -> perfectly uniform work, 2 blocks/CU.
// K/V double-buffered (T3/T4: counted vmcnt(8), loads in flight across
// barriers); both q-tiles consume the same staged K/V tile. Fixed-m softmax
// (scale*log2e folded into Q). sP bounce XOR-swizzled -> conflict-free.
template <bool MASKED>
DEVI void attn_body(const bf16_t* __restrict__ Qp, const char* __restrict__ Kg,
                    const char* __restrict__ Vg, const int* __restrict__ mp,
                    unsigned short* __restrict__ cp, char* sKc, char* sVc,
                    unsigned short* __restrict__ pb, int b, int bh,
                    int qbS, int qbL) {
  const int tid = threadIdx.x, lane = tid & 63, wid = tid >> 6;
  const int l16 = lane & 15, quad = lane >> 4;
  const int nS = (qbS >> 1) + 1, nL = (qbL >> 1) + 1;
  const int qwS = qbS * 64 + wid * 16, qwL = qbL * 64 + wid * 16;
  const int qcS = qwS + l16, qcL = qwL + l16;
  const int swz = (l16 & 7) << 4;

  // Q as B-operand: B[k=d=quad*8+j][n=q=l16]
  bf16x8 qSf0 = *(const bf16x8*)(Qp + (size_t)(qwS + l16) * Dh + quad * 8);
  bf16x8 qSf1 = *(const bf16x8*)(Qp + (size_t)(qwS + l16) * Dh + 32 + quad * 8);
  bf16x8 qLf0 = *(const bf16x8*)(Qp + (size_t)(qwL + l16) * Dh + quad * 8);
  bf16x8 qLf1 = *(const bf16x8*)(Qp + (size_t)(qwL + l16) * Dh + 32 + quad * 8);

  // staging: wave w fills K sections 4w..4w+3 and V sections 4w..4w+3
  int sLds[4], kGo[4], vGo[4];
#pragma unroll
  for (int i = 0; i < 4; ++i) {
    int sk = wid * 4 + i, g = sk >> 1, c = sk & 1;
    sLds[i] = sk * 1024;                                       // +lane*16 implicit
    kGo[i] = ((g * 16 + l16) * Dh + c * 32 + quad * 8) * 2;
    vGo[i] = ((wid * 16 + l16) * S + i * 32 + quad * 8) * 2;   // dt=wid, kc=i
  }

  f32x4 accL[4] = {}, accS[4] = {};
  float lsumL = 0.f, lsumS = 0.f;

  // prologue: stage tile 0 -> buffer 0
#pragma unroll
  for (int i = 0; i < 4; ++i) {
    async_copy16(sKc + sLds[i], Kg + kGo[i]);
    async_copy16(sVc + sLds[i], Vg + vGo[i]);
  }

  for (int kt = 0; kt < nL; ++kt) {
    const int cur = kt & 1;
    const int kb = kt * 128;
    if (kt + 1 < nL) {
      // issue next tile's 8 loads into the other buffer; wait only for the
      // PREVIOUS 8 (covered by last iter's compute) -> loads stay in flight
      const char* Kn = Kg + (size_t)(kb + 128) * (Dh * 2);
      const char* Vn = Vg + (size_t)(kb + 128) * 2;
      char* kd = sKc + (cur ^ 1) * 16384;
      char* vd = sVc + (cur ^ 1) * 16384;
#pragma unroll
      for (int i = 0; i < 4; ++i) {
        async_copy16(kd + sLds[i], Kn + kGo[i]);
        async_copy16(vd + sLds[i], Vn + vGo[i]);
      }
      if (!MASKED) { VMCNT8(); }
    } else if (!MASKED) {
      VMCNT0();
    }
    int mk0 = 0, mk1 = 0;
    if (MASKED) {
      mk0 = mp[kb + lane];
      mk1 = mp[kb + 64 + lane];
      VMCNT0();
    }
    __builtin_amdgcn_s_barrier();            // staged tile kt visible everywhere

    const bf16_t* sKt = (const bf16_t*)(sKc + cur * 16384);
    const bf16_t* sVt = (const bf16_t*)(sVc + cur * 16384);
    const bool doS = kt < nS;

    // S^T = K.Q^T for both q-tiles, reusing each K fragment
    f32x4 stL[8], stS[8];
    __builtin_amdgcn_s_setprio(1);
#pragma unroll
    for (int g = 0; g < 8; ++g) {
      bf16x8 kf0 = *(const bf16x8*)(sKt + (g * 2 + 0) * 512 + lane * 8);
      bf16x8 kf1 = *(const bf16x8*)(sKt + (g * 2 + 1) * 512 + lane * 8);
      f32x4 z = {};
      z = __builtin_amdgcn_mfma_f32_16x16x32_bf16(kf0, qLf0, z, 0, 0, 0);
      z = __builtin_amdgcn_mfma_f32_16x16x32_bf16(kf1, qLf1, z, 0, 0, 0);
      stL[g] = z;                             // S^T[key=g*16+quad*4+r][q=l16]
      if (doS) {
        f32x4 y = {};
        y = __builtin_amdgcn_mfma_f32_16x16x32_bf16(kf0, qSf0, y, 0, 0, 0);
        y = __builtin_amdgcn_mfma_f32_16x16x32_bf16(kf1, qSf1, y, 0, 0, 0);
        stS[g] = y;
      }
    }
    __builtin_amdgcn_s_setprio(0);

    if (MASKED) {
      unsigned long long dm0 = __ballot(mk0 == 0);
      unsigned long long dm1 = __ballot(mk1 == 0);
      if (dm0 | dm1) {
#pragma unroll
        for (int g = 0; g < 8; ++g) {
          unsigned long long dm = (g < 4) ? dm0 : dm1;
#pragma unroll
          for (int r = 0; r < 4; ++r)
            if ((dm >> ((g & 3) * 16 + quad * 4 + r)) & 1ull) {
              stL[g][r] = -1e30f;
              if (doS) stS[g][r] = -1e30f;
            }
        }
      }
    }
    // causal mask: only the diagonal tile of each q-tile
    if (kt == nL - 1) {
#pragma unroll
      for (int g = 0; g < 8; ++g)
#pragma unroll
        for (int r = 0; r < 4; ++r)
          if (kb + g * 16 + quad * 4 + r > qcL) stL[g][r] = -1e30f;
    }
    if (doS && kt == nS - 1) {
#pragma unroll
      for (int g = 0; g < 8; ++g)
#pragma unroll
        for (int r = 0; r < 4; ++r)
          if (kb + g * 16 + quad * 4 + r > qcS) stS[g][r] = -1e30f;
    }

    // ---- long tile: p = exp2(s), bounce to B-layout, ctx^T += V^T.P^T
#pragma unroll
    for (int g = 0; g < 8; ++g) {
      float e0 = exp2f(stL[g][0]), e1 = exp2f(stL[g][1]);
      float e2 = exp2f(stL[g][2]), e3 = exp2f(stL[g][3]);
      lsumL += (e0 + e1) + (e2 + e3);
      bf16x4 pk = { (bf16_t)e0, (bf16_t)e1, (bf16_t)e2, (bf16_t)e3 };
      *(bf16x4*)((char*)pb + ((l16 * 256 + g * 32 + quad * 8) ^ swz)) = pk;
    }
    {
      bf16x8 pf[4];
#pragma unroll
      for (int kc = 0; kc < 4; ++kc)
        pf[kc] = *(const bf16x8*)((const char*)pb + ((l16 * 256 + kc * 64 + quad * 16) ^ swz));
      __builtin_amdgcn_s_setprio(1);
#pragma unroll
      for (int dt = 0; dt < 4; ++dt)
#pragma unroll
        for (int kc = 0; kc < 4; ++kc) {
          bf16x8 vf = *(const bf16x8*)(sVt + (dt * 4 + kc) * 512 + lane * 8);
          accL[dt] = __builtin_amdgcn_mfma_f32_16x16x32_bf16(vf, pf[kc], accL[dt], 0, 0, 0);
        }
      __builtin_amdgcn_s_setprio(0);
    }
    // ---- short tile (same staged K/V; per-wave sP reused, DS is in-order)
    if (doS) {
#pragma unroll
      for (int g = 0; g < 8; ++g) {
        float e0 = exp2f(stS[g][0]), e1 = exp2f(stS[g][1]);
        float e2 = exp2f(stS[g][2]), e3 = exp2f(stS[g][3]);
        lsumS += (e0 + e1) + (e2 + e3);
        bf16x4 pk = { (bf16_t)e0, (bf16_t)e1, (bf16_t)e2, (bf16_t)e3 };
        *(bf16x4*)((char*)pb + ((l16 * 256 + g * 32 + quad * 8) ^ swz)) = pk;
      }
      bf16x8 pf[4];
#pragma unroll
      for (int kc = 0; kc < 4; ++kc)
        pf[kc] = *(const bf16x8*)((const char*)pb + ((l16 * 256 + kc * 64 + quad * 16) ^ swz));
      __builtin_amdgcn_s_setprio(1);
#pragma unroll
      for (int dt = 0; dt < 4; ++dt)
#pragma unroll
        for (int kc = 0; kc < 4; ++kc) {
          bf16x8 vf = *(const bf16x8*)(sVt + (dt * 4 + kc) * 512 + lane * 8);
          accS[dt] = __builtin_amdgcn_mfma_f32_16x16x32_bf16(vf, pf[kc], accS[dt], 0, 0, 0);
        }
      __builtin_amdgcn_s_setprio(0);
    }
    __builtin_amdgcn_s_barrier();            // tile kt fully consumed
  }

  lsumL += __shfl_xor(lsumL, 16); lsumL += __shfl_xor(lsumL, 32);
  lsumS += __shfl_xor(lsumS, 16); lsumS += __shfl_xor(lsumS, 32);
  const float invL = 1.0f / lsumL, invS = 1.0f / lsumS;
  const size_t trL = ((size_t)(b * S + qwL + l16)) * N + (size_t)(bh & 15) * Dh;
  const size_t trS = ((size_t)(b * S + qwS + l16)) * N + (size_t)(bh & 15) * Dh;
#pragma unroll
  for (int dt = 0; dt < 4; ++dt) {
    u16x4 oL = { f2bf(accL[dt][0] * invL), f2bf(accL[dt][1] * invL),
                 f2bf(accL[dt][2] * invL), f2bf(accL[dt][3] * invL) };
    *(u16x4*)&cp[trL + dt * 16 + quad * 4] = oL;
    u16x4 oS = { f2bf(accS[dt][0] * invS), f2bf(accS[dt][1] * invS),
                 f2bf(accS[dt][2] * invS), f2bf(accS[dt][3] * invS) };
    *(u16x4*)&cp[trS + dt * 16 + quad * 4] = oS;
  }
}

__global__ __launch_bounds__(256, 2) void attn_kernel(
    const bf16_t* __restrict__ Q, const bf16_t* __restrict__ Kb,
    const bf16_t* __restrict__ Vt, const int* __restrict__ mask,
    bf16_t* __restrict__ ctx) {
  __shared__ bf16_t sK[2][8192];               // 32KB K double-buffer
  __shared__ bf16_t sV[2][8192];               // 32KB V double-buffer
  __shared__ unsigned short sP[4][2048];       // 16KB per-wave P^T bounce (XOR-swz)

  const int idx = blockIdx.x;                  // 512 blocks
  const int j  = idx >> 5;                     // 0..15
  const int bh = idx & 31;
  const int b  = bh >> 4;
  const int lane = threadIdx.x & 63, wid = threadIdx.x >> 6;

  const bf16_t* Qp = Q + (size_t)bh * S * Dh;
  const char*   Kg = (const char*)(Kb + (size_t)bh * S * Dh);
  const char*   Vg = (const char*)(Vt + (size_t)bh * Dh * S);
  const int*    mp = mask + b * S;

  // one pass over the mask row: all-alive -> fast path with zero in-loop
  // mask vmem (keeps the counted-vmcnt accounting exact)
  int dead = 0;
  const int4* mp4 = (const int4*)mp;
  for (int c = lane; c < S / 4; c += 64) {
    int4 m = mp4[c];
    dead |= (m.x == 0) | (m.y == 0) | (m.z == 0) | (m.w == 0);
  }
  const bool anydead = __ballot(dead != 0) != 0ull;

  unsigned short* cp = (unsigned short*)ctx;
  if (!anydead)
    attn_body<false>(Qp, Kg, Vg, mp, cp, (char*)&sK[0][0], (char*)&sV[0][0],
                     &sP[wid][0], b, bh, j, 31 - j);
  else
    attn_body<true>(Qp, Kg, Vg, mp, cp, (char*)&sK[0][0], (char*)&sV[0][0],
                    &sP[wid][0], b, bh, j, 31 - j);
}

// ---------------- launcher ----------------

extern "C" void kernel_launch(void* const* d_in, const int* in_sizes, int n_in,
                              void* d_out, int out_size, void* d_ws, size_t ws_size,
                              hipStream_t stream) {
  const float* x  = (const float*)d_in[0];
  const int*  msk = (const int*)d_in[1];
  const float* Wq = (const float*)d_in[2];
  const float* bq = (const float*)d_in[3];
  const float* Wk = (const float*)d_in[4];
  const float* bk = (const float*)d_in[5];
  const float* Wv = (const float*)d_in[6];
  const float* bv = (const float*)d_in[7];
  const float* Wo = (const float*)d_in[8];
  const float* bo = (const float*)d_in[9];
  float* out = (float*)d_out;
  (void)in_sizes; (void)n_in; (void)out_size; (void)ws_size;

  char* ws = (char*)d_ws;
  bf16_t* xb   = (bf16_t*)(ws);                      // 8 MB  [4096][1024]
  bf16_t* WT   = (bf16_t*)(ws + (8u  << 20));        // 8 MB  4 x [1024][1024] (N-major)
  bf16_t* qkv  = (bf16_t*)(ws + (16u << 20));        // 24 MB Q,K,V each [B,H,S,D]
  bf16_t* Qb   = qkv;
  bf16_t* Kbuf = qkv + (size_t)1 * M * N;
  bf16_t* Vb   = qkv + (size_t)2 * M * N;
  bf16_t* Vt   = xb;                                  // alias: xb dead after QKV GEMM
  bf16_t* ctx  = Vb;                                  // alias: V[B,H,S,D] dead after vtrans
  float* ropeC = (float*)(ws + (40u << 20));          // 256 KB
  float* ropeS = ropeC + (size_t)S * 32;              // 256 KB

  prep_kernel<<<5376, 256, 0, stream>>>(x, xb, Wq, Wk, Wv, Wo, WT, ropeC, ropeS);
  gemm_qkv_kernel<<<dim3(8, 32, 3), 256, 0, stream>>>(xb, WT, bq, bk, bv, qkv, ropeC, ropeS);
  vtrans_kernel<<<dim3(32, 32), 256, 0, stream>>>(Vb, Vt);
  attn_kernel<<<512, 256, 0, stream>>>(Qb, Kbuf, Vt, msk, ctx);
  gemm_o_kernel<<<dim3(8, 64), 256, 0, stream>>>(ctx, WT + (size_t)3 * Kd * N, bo, out);
}

// Round 2
// 196.123 us; speedup vs baseline: 1.0404x; 1.0404x over previous
//
#include <hip/hip_runtime.h>
#include <cstdint>
#include <cstddef>

#define DEVI __device__ __forceinline__

typedef __bf16 bf16_t;
typedef __bf16 bf16x4 __attribute__((ext_vector_type(4)));
typedef __bf16 bf16x8 __attribute__((ext_vector_type(8)));
typedef float  f32x4  __attribute__((ext_vector_type(4)));
typedef float  f32x16 __attribute__((ext_vector_type(16)));
typedef unsigned short u16x4 __attribute__((ext_vector_type(4)));
typedef unsigned int   u32x4 __attribute__((ext_vector_type(4)));

static constexpr int Bz = 2, S = 2048, E = 1024, H = 16, Dh = 64;
static constexpr int M  = Bz * S;   // 4096 tokens
static constexpr int N  = H * Dh;   // 1024
static constexpr int Kd = E;        // 1024

DEVI unsigned short f2bf(float f) {
  unsigned u = __builtin_bit_cast(unsigned, f);
  return (unsigned short)((u + 0x7fffu + ((u >> 16) & 1u)) >> 16);
}

DEVI void async_copy16(void* lds, const void* g) {
  __builtin_amdgcn_global_load_lds((__attribute__((address_space(1))) void*)(g),
                                   (__attribute__((address_space(3))) void*)(lds), 16, 0, 0);
}

DEVI void block_sync() { asm volatile("s_barrier" ::: "memory"); }
#define VMCNT4() asm volatile("s_waitcnt vmcnt(4)" ::: "memory")
#define VMCNT0() asm volatile("s_waitcnt vmcnt(0)" ::: "memory")

// pack two f32 -> dword of two bf16 (RNE)
DEVI unsigned cvtpk(float lo, float hi) {
  unsigned r;
  asm("v_cvt_pk_bf16_f32 %0, %1, %2" : "=v"(r) : "v"(lo), "v"(hi));
  return r;
}
// swap x's lanes 32-63 with y's lanes 0-31
DEVI void swap32(unsigned& x, unsigned& y) {
  asm("v_permlane32_swap_b32 %0, %1" : "+v"(x), "+v"(y));
}

// ---------------- fused prep: convx | wtrans | rope table ----------------
__global__ void prep_kernel(const float* __restrict__ x, bf16_t* __restrict__ xb,
                            const float* __restrict__ Wq, const float* __restrict__ Wk,
                            const float* __restrict__ Wv, const float* __restrict__ Wo,
                            bf16_t* __restrict__ WtBase,
                            float* __restrict__ ropeC, float* __restrict__ ropeS) {
  __shared__ unsigned short tile[64][68];
  const int blk = blockIdx.x, tid = threadIdx.x;
  if (blk < 4096) {
    // x fp32 -> bf16
    int i = blk * 256 + tid;
    float4 v = ((const float4*)x)[i];
    u16x4 o = { f2bf(v.x), f2bf(v.y), f2bf(v.z), f2bf(v.w) };
    ((u16x4*)xb)[i] = o;
  } else if (blk < 5120) {
    // weight fp32 [K][N] -> bf16 [N][K]
    const int i = blk - 4096;
    const int z = i >> 8, rest = i & 255;
    const int n0 = (rest & 15) * 64, k0 = (rest >> 4) * 64;
    const float* W = (z == 0) ? Wq : (z == 1) ? Wk : (z == 2) ? Wv : Wo;
    unsigned short* T = (unsigned short*)(WtBase + (size_t)z * Kd * N);
    for (int e = tid; e < 1024; e += 256) {
      int r = e >> 4, c4 = (e & 15) * 4;
      float4 v = *(const float4*)(W + (size_t)(k0 + r) * N + n0 + c4);
      u16x4 o = { f2bf(v.x), f2bf(v.y), f2bf(v.z), f2bf(v.w) };
      *(u16x4*)&tile[r][c4] = o;
    }
    __syncthreads();
    for (int e = tid; e < 1024; e += 256) {
      int r = e >> 4, c4 = (e & 15) * 4;
      u16x4 o = { tile[c4][r], tile[c4 + 1][r], tile[c4 + 2][r], tile[c4 + 3][r] };
      *(u16x4*)&T[(size_t)(n0 + r) * Kd + k0 + c4] = o;
    }
  } else {
    int i = (blk - 5120) * 256 + tid;            // 65536 = 2048*32
    int pos = i >> 5, j = i & 31;
    float inv = exp2f(-(float)j * 0.41524101186092029f);   // log2(10000)/32
    float ang = (float)pos * inv;
    ropeC[i] = cosf(ang);
    ropeS[i] = sinf(ang);
  }
}

// bf16 [BH][S][D] -> bf16 [BH][D][S]
__global__ void vtrans_kernel(const bf16_t* __restrict__ V, bf16_t* __restrict__ Vt) {
  __shared__ unsigned short tile[64][68];
  const int bh = blockIdx.y;
  const int s0 = blockIdx.x * 64;
  const unsigned short* Vp = (const unsigned short*)V + (size_t)bh * S * Dh;
  unsigned short* Tp = (unsigned short*)Vt + (size_t)bh * Dh * S;
  const int tid = threadIdx.x;
  for (int e = tid; e < 1024; e += 256) {
    int r = e >> 4, c4 = (e & 15) * 4;
    u16x4 v = *(const u16x4*)(Vp + (size_t)(s0 + r) * Dh + c4);
    *(u16x4*)&tile[r][c4] = v;
  }
  __syncthreads();
  for (int e = tid; e < 1024; e += 256) {
    int d = e >> 4, s4 = (e & 15) * 4;
    u16x4 o = { tile[s4][d], tile[s4 + 1][d], tile[s4 + 2][d], tile[s4 + 3][d] };
    *(u16x4*)&Tp[(size_t)d * S + s0 + s4] = o;
  }
}

// ---------------- GEMM core (128x128 tile, BK=32, global_load_lds) ----------------

DEVI void gemm_mainloop(const bf16_t* __restrict__ A, const bf16_t* __restrict__ Bt,
                        bf16_t* sA, bf16_t* sB, int m0, int n0, f32x4 (&acc)[4][4]) {
  const int tid  = threadIdx.x;
  const int lane = tid & 63;
  const int wid  = tid >> 6;
  const int l16  = lane & 15;
  const int quad = lane >> 4;
  const int wm = (wid >> 1) * 64;
  const int wn = (wid & 1) * 64;
  const int o0 = wid * 2048 + lane * 16;   // byte offset within 8KB tile
  const int o1 = o0 + 1024;
  const int r0 = o0 >> 6, c0 = o0 & 63;
  const int r1 = o1 >> 6, c1 = o1 & 63;
  const char* Ab = (const char*)A;
  const char* Bb = (const char*)Bt;
  char* sAc = (char*)sA;
  char* sBc = (char*)sB;

  for (int k0 = 0; k0 < Kd; k0 += 32) {
    __syncthreads();
    async_copy16(sAc + wid * 2048,        Ab + ((size_t)(m0 + r0) * Kd + k0) * 2 + c0);
    async_copy16(sAc + wid * 2048 + 1024, Ab + ((size_t)(m0 + r1) * Kd + k0) * 2 + c1);
    async_copy16(sBc + wid * 2048,        Bb + ((size_t)(n0 + r0) * Kd + k0) * 2 + c0);
    async_copy16(sBc + wid * 2048 + 1024, Bb + ((size_t)(n0 + r1) * Kd + k0) * 2 + c1);
    __syncthreads();
    bf16x8 af[4], bfv[4];
#pragma unroll
    for (int mi = 0; mi < 4; ++mi)
      af[mi] = *(const bf16x8*)(sA + (wm + mi * 16 + l16) * 32 + quad * 8);
#pragma unroll
    for (int ni = 0; ni < 4; ++ni)
      bfv[ni] = *(const bf16x8*)(sB + (wn + ni * 16 + l16) * 32 + quad * 8);
#pragma unroll
    for (int mi = 0; mi < 4; ++mi)
#pragma unroll
      for (int ni = 0; ni < 4; ++ni)
        acc[mi][ni] = __builtin_amdgcn_mfma_f32_16x16x32_bf16(af[mi], bfv[ni], acc[mi][ni], 0, 0, 0);
  }
}

// z = 0:Q(RoPE+scale) 1:K(RoPE) 2:V ; out layout [B,H,S,D] bf16
__global__ __launch_bounds__(256, 3) void gemm_qkv_kernel(
    const bf16_t* __restrict__ xb, const bf16_t* __restrict__ WtBase,
    const float* __restrict__ bq, const float* __restrict__ bk, const float* __restrict__ bv,
    bf16_t* __restrict__ outBase,
    const float* __restrict__ ropeC, const float* __restrict__ ropeS) {
  __shared__ bf16_t sA[4096], sB[4096];
  const int z = blockIdx.z;
  const bf16_t* Bt = WtBase + (size_t)z * Kd * N;
  const float* bias = (z == 0) ? bq : (z == 1) ? bk : bv;
  unsigned short* outp = (unsigned short*)(outBase + (size_t)z * M * N);
  const int n0 = blockIdx.x * 128, m0 = blockIdx.y * 128;
  f32x4 acc[4][4] = {};
  gemm_mainloop(xb, Bt, sA, sB, m0, n0, acc);

  const int tid = threadIdx.x, lane = tid & 63, wid = tid >> 6;
  const int l16 = lane & 15, quad = lane >> 4;
  const int wm = (wid >> 1) * 64, wn = (wid & 1) * 64;
  const int cbase = n0 + wn;          // 64-aligned -> one head per wave slab
  const int h = cbase >> 6;

  if (z < 2) {
    // Q gets 0.125 (=1/sqrt(D)) * log2(e) folded in so attention can use exp2
    const float qs = (z == 0) ? 0.18033688011112042f : 1.0f;
#pragma unroll
    for (int mi = 0; mi < 4; ++mi)
#pragma unroll
      for (int r = 0; r < 4; ++r) {
        int t = m0 + wm + mi * 16 + quad * 4 + r;
        int bb = t >> 11, s = t & (S - 1);
        size_t obase = ((size_t)(bb * H + h) * S + s) * Dh;
#pragma unroll
        for (int np = 0; np < 2; ++np) {
          int j = np * 16 + l16;                 // = d (low half), d-32 (high half)
          float cc = ropeC[s * 32 + j];
          float ss = ropeS[s * 32 + j];
          float xlo = acc[mi][np][r]     + bias[cbase + j];
          float xhi = acc[mi][np + 2][r] + bias[cbase + j + 32];
          outp[obase + j]      = f2bf((xlo * cc - xhi * ss) * qs);
          outp[obase + j + 32] = f2bf((xhi * cc + xlo * ss) * qs);
        }
      }
  } else {
#pragma unroll
    for (int mi = 0; mi < 4; ++mi)
#pragma unroll
      for (int r = 0; r < 4; ++r) {
        int t = m0 + wm + mi * 16 + quad * 4 + r;
        int bb = t >> 11, s = t & (S - 1);
        size_t obase = ((size_t)(bb * H + h) * S + s) * Dh;
#pragma unroll
        for (int ni = 0; ni < 4; ++ni) {
          int d = ni * 16 + l16;
          outp[obase + d] = f2bf(acc[mi][ni][r] + bias[cbase + d]);
        }
      }
  }
}

// output GEMM: 64(m) x 128(n) tiles -> 512 blocks (2/CU)
__global__ __launch_bounds__(256, 4) void gemm_o_kernel(
    const bf16_t* __restrict__ A, const bf16_t* __restrict__ Bt,
    const float* __restrict__ bias, float* __restrict__ out) {
  __shared__ bf16_t sA[2048], sB[4096];     // 4KB A (64x32), 8KB B (128x32)
  const int n0 = blockIdx.x * 128, m0 = blockIdx.y * 64;
  const int tid = threadIdx.x, lane = tid & 63, wid = tid >> 6;
  const int l16 = lane & 15, quad = lane >> 4;
  const int wm = (wid >> 1) * 32, wn = (wid & 1) * 64;
  const int rowoff = lane >> 2, col8 = (lane & 3) * 8;
  const char* Ab = (const char*)A;
  const char* Bb = (const char*)Bt;
  char* sAc = (char*)sA;
  char* sBc = (char*)sB;
  f32x4 acc[2][4] = {};

  for (int k0 = 0; k0 < Kd; k0 += 32) {
    __syncthreads();
    async_copy16(sAc + wid * 1024,
                 Ab + ((size_t)(m0 + wid * 16 + rowoff) * Kd + k0 + col8) * 2);
    async_copy16(sBc + (wid * 2) * 1024,
                 Bb + ((size_t)(n0 + wid * 32 + rowoff) * Kd + k0 + col8) * 2);
    async_copy16(sBc + (wid * 2 + 1) * 1024,
                 Bb + ((size_t)(n0 + wid * 32 + 16 + rowoff) * Kd + k0 + col8) * 2);
    __syncthreads();
    bf16x8 af[2], bfv[4];
#pragma unroll
    for (int mi = 0; mi < 2; ++mi)
      af[mi] = *(const bf16x8*)(sA + (wm + mi * 16 + l16) * 32 + quad * 8);
#pragma unroll
    for (int ni = 0; ni < 4; ++ni)
      bfv[ni] = *(const bf16x8*)(sB + (wn + ni * 16 + l16) * 32 + quad * 8);
#pragma unroll
    for (int mi = 0; mi < 2; ++mi)
#pragma unroll
      for (int ni = 0; ni < 4; ++ni)
        acc[mi][ni] = __builtin_amdgcn_mfma_f32_16x16x32_bf16(af[mi], bfv[ni], acc[mi][ni], 0, 0, 0);
  }
#pragma unroll
  for (int mi = 0; mi < 2; ++mi)
#pragma unroll
    for (int r = 0; r < 4; ++r) {
      int t = m0 + wm + mi * 16 + quad * 4 + r;
#pragma unroll
      for (int ni = 0; ni < 4; ++ni) {
        int c = n0 + wn + ni * 16 + l16;
        out[(size_t)t * N + c] = acc[mi][ni][r] + bias[c];
      }
    }
}

// ---------------- flash attention (32x32 MFMA, split-K, in-register P) ----------------
// 512 blocks x 512 threads. Block (qb, bh): 128 q rows, 8 waves.
//   wave = (grp = wid>>2, w4 = wid&3): grp 0 handles keys [0, (qb+1)*64),
//   grp 1 handles [(qb+1)*64, (qb+1)*128); each wave owns 32 q rows (w4).
// Fixed-m softmax (scale*log2e folded into Q) -> split-K combine is additive.
// QK^T swapped (K as A-operand) so P lands in D-layout; converted to the PV
// B-operand with v_cvt_pk_bf16_f32 + v_permlane32_swap_b32 (no LDS bounce).
// K/V staged in fragment order via global_load_lds, double-buffered, counted
// vmcnt(4) -> loads stay in flight across barriers.
template <bool MASKED>
DEVI void attn32_body(const bf16_t* __restrict__ Qp, const char* __restrict__ Kg,
                      const char* __restrict__ Vg, const int* __restrict__ mp,
                      unsigned short* __restrict__ cp, char* lds,
                      int b, int bh, int qb) {
  const int tid = threadIdx.x, lane = tid & 63, wid = tid >> 6;
  const int grp = wid >> 2, w4 = wid & 3;
  const int l32 = lane & 31, hi = lane >> 5;

  const int qw = qb * 128 + w4 * 32;       // wave's first q row
  const int qg = qw + l32;                 // this lane's q (as D-col)
  const int nIt = qb + 1;                  // 64-key tiles per group
  const int gk0 = grp * nIt * 64;          // group key base
  char* gB = lds + grp * 32768;            // per-group 32KB (2 x 16KB dbuf)

  // Q fragments (B-operand): B[k = hi*8+j][n = q = l32], d-chunk c
  bf16x8 qf[4];
#pragma unroll
  for (int c = 0; c < 4; ++c)
    qf[c] = *(const bf16x8*)(Qp + (size_t)(qw + l32) * Dh + c * 16 + hi * 8);
  // force the Q-load waits to land here (pre-loop), keeping in-loop vmcnt exact
  asm volatile("" :: "v"((float)qf[3][7]));

  // staging: wave stages K sections {w4*2, w4*2+1} and V sections {w4*2, w4*2+1}
  // K section s = a*4+c : element (key = l32, d = c*16 + hi*8 + j) of chunk a
  // V section s = e*4+kc: element (d = e*32 + l32, key = kc*16 + hi*8 + j)
  int kLds[2], vLds[2], kOff[2], vOff[2];
#pragma unroll
  for (int i = 0; i < 2; ++i) {
    const int s = w4 * 2 + i;
    const int a = s >> 2, c = s & 3;
    kLds[i] = s * 1024;
    kOff[i] = ((a * 32 + l32) * Dh + c * 16 + hi * 8) * 2;
    vLds[i] = 8192 + s * 1024;
    vOff[i] = ((s >> 2) * 32 + l32) * (S * 2) + (((s & 3) * 16 + hi * 8) * 2);
  }

  f32x16 cacc0 = {}, cacc1 = {};
  float lsum = 0.f;

  // prologue: stage tile 0 -> buffer 0
  {
    const char* ks = Kg + (size_t)gk0 * (Dh * 2);
    const char* vs = Vg + (size_t)gk0 * 2;
    async_copy16(gB + kLds[0], ks + kOff[0]);
    async_copy16(gB + kLds[1], ks + kOff[1]);
    async_copy16(gB + vLds[0], vs + vOff[0]);
    async_copy16(gB + vLds[1], vs + vOff[1]);
  }

  for (int kt = 0; kt < nIt; ++kt) {
    const int cur = kt & 1;
    const int kb = gk0 + kt * 64;
    if (kt + 1 < nIt) {
      char* dst = gB + (cur ^ 1) * 16384;
      const char* ks = Kg + (size_t)(kb + 64) * (Dh * 2);
      const char* vs = Vg + (size_t)(kb + 64) * 2;
      async_copy16(dst + kLds[0], ks + kOff[0]);
      async_copy16(dst + kLds[1], ks + kOff[1]);
      async_copy16(dst + vLds[0], vs + vOff[0]);
      async_copy16(dst + vLds[1], vs + vOff[1]);
      if (!MASKED) { VMCNT4(); }       // wait only for tile kt's 4 copies
    } else if (!MASKED) {
      VMCNT0();
    }
    unsigned long long dm = 0;
    if (MASKED) {
      int mk = mp[kb + lane];
      VMCNT0();
      dm = __ballot(mk == 0);
    }
    block_sync();                       // tile kt visible to all waves

    const bf16_t* sK = (const bf16_t*)(gB + cur * 16384);
    const bf16_t* sV = (const bf16_t*)(gB + cur * 16384 + 8192);
    const bool needC = (kb + 63 > qw);  // causal mask touches this tile?

#pragma unroll
    for (int a = 0; a < 2; ++a) {
      // S^T(32 keys x 32 q) = K . Q^T over d (4 chunks of 16)
      f32x16 st = {};
      __builtin_amdgcn_s_setprio(1);
#pragma unroll
      for (int c = 0; c < 4; ++c) {
        bf16x8 kf = *(const bf16x8*)(sK + (a * 4 + c) * 512 + lane * 8);
        st = __builtin_amdgcn_mfma_f32_32x32x16_bf16(kf, qf[c], st, 0, 0, 0);
      }
      __builtin_amdgcn_s_setprio(0);
      // D layout: col = q = l32, key-in-32 = (r&3) + 8*(r>>2) + 4*hi
      if (MASKED && dm) {
#pragma unroll
        for (int r = 0; r < 16; ++r)
          if ((dm >> (a * 32 + (r & 3) + 8 * (r >> 2) + 4 * hi)) & 1ull) st[r] = -1e30f;
      }
      if (needC) {
        const int kbase = kb + a * 32 + 4 * hi - qg;
#pragma unroll
        for (int r = 0; r < 16; ++r)
          if (kbase + (r & 3) + 8 * (r >> 2) > 0) st[r] = -1e30f;
      }
      // p = exp2(s) (fixed m); pack pairs to bf16 dwords
      unsigned P0[4], P1[4];
#pragma unroll
      for (int m = 0; m < 4; ++m) {
        float p0 = exp2f(st[4 * m + 0]), p1 = exp2f(st[4 * m + 1]);
        float p2 = exp2f(st[4 * m + 2]), p3 = exp2f(st[4 * m + 3]);
        lsum += (p0 + p1) + (p2 + p3);
        P0[m] = cvtpk(p0, p1);
        P1[m] = cvtpk(p2, p3);
      }
      // permlane32_swap -> PV B-operand frags (keys a*32+[0,16) and a*32+[16,32))
      swap32(P0[0], P0[1]); swap32(P1[0], P1[1]);
      swap32(P0[2], P0[3]); swap32(P1[2], P1[3]);
      u32x4 t0 = { P0[0], P1[0], P0[1], P1[1] };
      u32x4 t1 = { P0[2], P1[2], P0[3], P1[3] };
      const bf16x8 f0 = __builtin_bit_cast(bf16x8, t0);
      const bf16x8 f1 = __builtin_bit_cast(bf16x8, t1);
      // ctx^T += V^T . P^T
      __builtin_amdgcn_s_setprio(1);
      {
        bf16x8 v00 = *(const bf16x8*)(sV + (0 + a * 2 + 0) * 512 + lane * 8);
        cacc0 = __builtin_amdgcn_mfma_f32_32x32x16_bf16(v00, f0, cacc0, 0, 0, 0);
        bf16x8 v01 = *(const bf16x8*)(sV + (0 + a * 2 + 1) * 512 + lane * 8);
        cacc0 = __builtin_amdgcn_mfma_f32_32x32x16_bf16(v01, f1, cacc0, 0, 0, 0);
        bf16x8 v10 = *(const bf16x8*)(sV + (4 + a * 2 + 0) * 512 + lane * 8);
        cacc1 = __builtin_amdgcn_mfma_f32_32x32x16_bf16(v10, f0, cacc1, 0, 0, 0);
        bf16x8 v11 = *(const bf16x8*)(sV + (4 + a * 2 + 1) * 512 + lane * 8);
        cacc1 = __builtin_amdgcn_mfma_f32_32x32x16_bf16(v11, f1, cacc1, 0, 0, 0);
      }
      __builtin_amdgcn_s_setprio(0);
    }
    block_sync();                       // buf[cur] fully consumed
  }

  // ---- split-K combine: grp1 -> LDS, grp0 adds, normalizes, writes ----
  float* cm = (float*)lds + (size_t)w4 * 2112;   // per-subtile 8448B region
  if (grp == 1) {
#pragma unroll
    for (int r = 0; r < 16; ++r) cm[r * 64 + lane] = cacc0[r];
#pragma unroll
    for (int r = 0; r < 16; ++r) cm[(16 + r) * 64 + lane] = cacc1[r];
    cm[2048 + lane] = lsum;
  }
  asm volatile("s_waitcnt lgkmcnt(0)" ::: "memory");
  block_sync();
  if (grp == 0) {
#pragma unroll
    for (int r = 0; r < 16; ++r) cacc0[r] += cm[r * 64 + lane];
#pragma unroll
    for (int r = 0; r < 16; ++r) cacc1[r] += cm[(16 + r) * 64 + lane];
    lsum += cm[2048 + lane];
    lsum += __shfl_xor(lsum, 32);
    const float inv = 1.0f / lsum;
    const size_t base = ((size_t)(b * S + qw + l32)) * N + (size_t)(bh & 15) * Dh;
#pragma unroll
    for (int m = 0; m < 4; ++m) {
      const int d0 = m * 8 + 4 * hi;     // d = (r&3) + 8m + 4hi
      u16x4 o0 = { f2bf(cacc0[4 * m + 0] * inv), f2bf(cacc0[4 * m + 1] * inv),
                   f2bf(cacc0[4 * m + 2] * inv), f2bf(cacc0[4 * m + 3] * inv) };
      *(u16x4*)&cp[base + d0] = o0;
      u16x4 o1 = { f2bf(cacc1[4 * m + 0] * inv), f2bf(cacc1[4 * m + 1] * inv),
                   f2bf(cacc1[4 * m + 2] * inv), f2bf(cacc1[4 * m + 3] * inv) };
      *(u16x4*)&cp[base + 32 + d0] = o1;
    }
  }
}

__global__ __launch_bounds__(512, 4) void attn_kernel(
    const bf16_t* __restrict__ Q, const bf16_t* __restrict__ Kb,
    const bf16_t* __restrict__ Vt, const int* __restrict__ mask,
    bf16_t* __restrict__ ctx) {
  __shared__ f32x4 ldsA[4096];                 // 64 KB

  const int idx = blockIdx.x;                  // 512 blocks
  const int g  = idx >> 5;                     // 0..15
  const int bh = idx & 31;
  const int qb = (g < 8) ? (15 - g) : (g - 8); // long halves first -> CU pairs sum to 17
  const int b  = bh >> 4;
  const int lane = threadIdx.x & 63;

  const bf16_t* Qp = Q + (size_t)bh * S * Dh;
  const char*   Kg = (const char*)(Kb + (size_t)bh * S * Dh);
  const char*   Vg = (const char*)(Vt + (size_t)bh * Dh * S);
  const int*    mp = mask + b * S;

  // one pass over the mask row: all-alive -> fast path with zero in-loop
  // mask vmem (keeps the counted-vmcnt accounting exact)
  int dead = 0;
  const int4* mp4 = (const int4*)mp;
  for (int c = lane; c < S / 4; c += 64) {
    int4 m = mp4[c];
    dead |= (m.x == 0) | (m.y == 0) | (m.z == 0) | (m.w == 0);
  }
  const bool anydead = __ballot(dead != 0) != 0ull;

  unsigned short* cp = (unsigned short*)ctx;
  if (!anydead)
    attn32_body<false>(Qp, Kg, Vg, mp, cp, (char*)ldsA, b, bh, qb);
  else
    attn32_body<true>(Qp, Kg, Vg, mp, cp, (char*)ldsA, b, bh, qb);
}

// ---------------- launcher ----------------

extern "C" void kernel_launch(void* const* d_in, const int* in_sizes, int n_in,
                              void* d_out, int out_size, void* d_ws, size_t ws_size,
                              hipStream_t stream) {
  const float* x  = (const float*)d_in[0];
  const int*  msk = (const int*)d_in[1];
  const float* Wq = (const float*)d_in[2];
  const float* bq = (const float*)d_in[3];
  const float* Wk = (const float*)d_in[4];
  const float* bk = (const float*)d_in[5];
  const float* Wv = (const float*)d_in[6];
  const float* bv = (const float*)d_in[7];
  const float* Wo = (const float*)d_in[8];
  const float* bo = (const float*)d_in[9];
  float* out = (float*)d_out;
  (void)in_sizes; (void)n_in; (void)out_size; (void)ws_size;

  char* ws = (char*)d_ws;
  bf16_t* xb   = (bf16_t*)(ws);                      // 8 MB  [4096][1024]
  bf16_t* WT   = (bf16_t*)(ws + (8u  << 20));        // 8 MB  4 x [1024][1024] (N-major)
  bf16_t* qkv  = (bf16_t*)(ws + (16u << 20));        // 24 MB Q,K,V each [B,H,S,D]
  bf16_t* Qb   = qkv;
  bf16_t* Kbuf = qkv + (size_t)1 * M * N;
  bf16_t* Vb   = qkv + (size_t)2 * M * N;
  bf16_t* Vt   = xb;                                  // alias: xb dead after QKV GEMM
  bf16_t* ctx  = Vb;                                  // alias: V[B,H,S,D] dead after vtrans
  float* ropeC = (float*)(ws + (40u << 20));          // 256 KB
  float* ropeS = ropeC + (size_t)S * 32;              // 256 KB

  prep_kernel<<<5376, 256, 0, stream>>>(x, xb, Wq, Wk, Wv, Wo, WT, ropeC, ropeS);
  gemm_qkv_kernel<<<dim3(8, 32, 3), 256, 0, stream>>>(xb, WT, bq, bk, bv, qkv, ropeC, ropeS);
  vtrans_kernel<<<dim3(32, 32), 256, 0, stream>>>(Vb, Vt);
  attn_kernel<<<512, 512, 0, stream>>>(Qb, Kbuf, Vt, msk, ctx);
  gemm_o_kernel<<<dim3(8, 64), 256, 0, stream>>>(ctx, WT + (size_t)3 * Kd * N, bo, out);
}